// Round 1
// baseline (280.545 us; speedup 1.0000x reference)
//
#include <hip/hip_runtime.h>
#include <hip/hip_bf16.h>

// Problem constants
#define D_MODEL 768
#define NH 12
#define HD 64
#define BATCH 4
#define SEQ 2048
#define BHN (BATCH*NH)        // 48
#define MROWS (BATCH*SEQ)     // 8192

typedef unsigned short u16;
typedef __attribute__((ext_vector_type(8))) short short8;
typedef __attribute__((ext_vector_type(4))) float f32x4;

__device__ inline u16 f2bf(float f){
  union { __hip_bfloat16 h; u16 u; } cv; cv.h = __float2bfloat16(f); return cv.u;
}

// async global->LDS, 16B per lane. LDS dest = wave-uniform base + lane*16.
__device__ inline void async_copy16(const void* g, void* l){
  __builtin_amdgcn_global_load_lds(
      (const __attribute__((address_space(1))) void*)g,
      (__attribute__((address_space(3))) void*)l, 16, 0, 0);
}

// ---------------- cast fp32 -> bf16, vectorized x4 ----------------
__global__ void cast4_kernel(const float* __restrict__ in, u16* __restrict__ out, int n4){
  int i = blockIdx.x*blockDim.x + threadIdx.x;
  if (i < n4){
    const float4 v = ((const float4*)in)[i];
    ushort4 o;
    o.x = f2bf(v.x); o.y = f2bf(v.y); o.z = f2bf(v.z); o.w = f2bf(v.w);
    ((ushort4*)out)[i] = o;
  }
}

// ---------------- transpose + cast: W[K][N] fp32 -> Wt[N][K] bf16 ----------------
__global__ void transpose_cast_kernel(const float* __restrict__ w, u16* __restrict__ wt,
                                      int K, int N){
  __shared__ u16 tile[64][65];
  int k0 = blockIdx.x*64, n0 = blockIdx.y*64;
  int c = threadIdx.x & 63, r0 = threadIdx.x >> 6;
  #pragma unroll
  for (int r = r0; r < 64; r += 4)
    tile[c][r] = f2bf(w[(size_t)(k0+r)*N + n0 + c]);
  __syncthreads();
  #pragma unroll
  for (int r = r0; r < 64; r += 4)
    wt[(size_t)(n0+r)*K + k0 + c] = tile[r][c];
}

// ---------------- bf16 GEMM: C[M,N] = A[M,K] @ Bt[N,K]^T ----------------
// 128x128 tile, BK=32, 256 threads = 4 waves in 2x2, each wave 64x64 (4x4 frags).
// EPI=0: out fp32 = acc + bias[n]
// EPI=1: qkv scatter: bf16 into q[bh][s][d], k[bh][s][d], vt[bh][d][s] (+bias)
template<int EPI>
__launch_bounds__(256)
__global__ void gemm_bf16(const u16* __restrict__ A, const u16* __restrict__ Bt,
                          const float* __restrict__ bias, float* __restrict__ outf,
                          u16* __restrict__ oq, u16* __restrict__ ok, u16* __restrict__ ovt,
                          int M, int N, int K)
{
  __shared__ alignas(16) u16 As[128*32];
  __shared__ alignas(16) u16 Bs[128*32];
  const int tid = threadIdx.x, wave = tid>>6, lane = tid&63;
  const int lr = lane&15, lg = lane>>4;
  const int m0 = blockIdx.x*128, n0 = blockIdx.y*128;
  const int wr = (wave>>1)*64, wc = (wave&1)*64;
  f32x4 acc[4][4] = {};
  const int srow = wave*32 + (lane>>2);   // staging row (+i*16)
  const int schk = lane&3;                // 16B chunk within 64B row

  for (int kt = 0; kt < K; kt += 32){
    __syncthreads();
    #pragma unroll
    for (int i = 0; i < 2; i++){
      int r = srow + i*16;
      async_copy16(A  + (size_t)(m0 + r)*K + kt + schk*8,
                   (char*)As + (wave*32 + i*16)*64);
      async_copy16(Bt + (size_t)(n0 + r)*K + kt + schk*8,
                   (char*)Bs + (wave*32 + i*16)*64);
    }
    __syncthreads();
    short8 a[4], b[4];
    #pragma unroll
    for (int mi = 0; mi < 4; mi++)
      a[mi] = *(const short8*)((const char*)As + (wr + mi*16 + lr)*64 + lg*16);
    #pragma unroll
    for (int ni = 0; ni < 4; ni++)
      b[ni] = *(const short8*)((const char*)Bs + (wc + ni*16 + lr)*64 + lg*16);
    #pragma unroll
    for (int mi = 0; mi < 4; mi++)
      #pragma unroll
      for (int ni = 0; ni < 4; ni++)
        acc[mi][ni] = __builtin_amdgcn_mfma_f32_16x16x32_bf16(a[mi], b[ni], acc[mi][ni], 0, 0, 0);
  }

  // epilogue: C row = (lane>>4)*4 + j, col = lane&15  [verified C/D layout]
  #pragma unroll
  for (int mi = 0; mi < 4; mi++)
  #pragma unroll
  for (int ni = 0; ni < 4; ni++)
  #pragma unroll
  for (int j = 0; j < 4; j++){
    int m = m0 + wr + mi*16 + lg*4 + j;
    int n = n0 + wc + ni*16 + lr;
    float v = acc[mi][ni][j] + bias[n];
    if (EPI == 0){
      outf[(size_t)m*N + n] = v;
    } else {
      int b_ = m >> 11, s = m & 2047;
      int t  = (n >= 1536) ? 2 : (n >= 768 ? 1 : 0);
      int hn = n - t*768;
      int h = hn >> 6, d = hn & 63;
      u16 bf = f2bf(v);
      size_t base = (size_t)(b_*NH + h);
      if (t == 0)      oq [(base*SEQ + s)*HD + d] = bf;
      else if (t == 1) ok [(base*SEQ + s)*HD + d] = bf;
      else             ovt[(base*HD + d)*SEQ + s] = bf;   // V stored transposed
    }
  }
}

// ---------------- flash attention ----------------
// grid (16 qtiles, 48 bh), 256 threads = 4 waves; wave owns 32 q rows.
// KV tiles of 64. K/V/Q LDS rows are 128B, XOR-swizzled (byte ^= (row&7)<<4)
// via pre-swizzled global_load_lds source.
__launch_bounds__(256)
__global__ void attn_kernel(const u16* __restrict__ q, const u16* __restrict__ k,
                            const u16* __restrict__ vt, u16* __restrict__ aout)
{
  __shared__ alignas(16) char smem[49152];
  char* Qs = smem;            // 128 x 128B = 16KB
  char* Ks = smem + 16384;    //  64 x 128B =  8KB
  char* Vs = smem + 24576;    //  64 x 128B =  8KB
  char* Ps = smem + 32768;    // 4 waves x 32 x 128B = 16KB

  const int qt = blockIdx.x, bh = blockIdx.y;
  const int tid = threadIdx.x, wave = tid>>6, lane = tid&63;
  const int lr = lane&15, lg = lane>>4;
  const int rloc = lane>>3, cc = lane&7;

  // stage Q tile (128 rows x 64 bf16), swizzled
  #pragma unroll
  for (int i = 0; i < 4; i++){
    int row = wave*32 + i*8 + rloc;
    int src = cc ^ (row & 7);
    async_copy16(q + ((size_t)bh*SEQ + qt*128 + row)*HD + src*8,
                 Qs + (wave*32 + i*8)*128);
  }
  __syncthreads();

  // Q fragments to registers (reused across all KV tiles)
  short8 aq[2][2];
  #pragma unroll
  for (int mi = 0; mi < 2; mi++)
    #pragma unroll
    for (int ks = 0; ks < 2; ks++){
      int row = wave*32 + mi*16 + lr;
      int byt = (ks*64 + lg*16) ^ ((row&7)<<4);
      aq[mi][ks] = *(const short8*)(Qs + row*128 + byt);
    }

  float mrow[2][4], lsum[2][4];
  f32x4 o[2][4] = {};
  #pragma unroll
  for (int mi = 0; mi < 2; mi++)
    #pragma unroll
    for (int j = 0; j < 4; j++){ mrow[mi][j] = -INFINITY; lsum[mi][j] = 0.f; }

  const int q0 = qt*128 + wave*32;
  const int nkv = (qt+1)*2;

  for (int kvb = 0; kvb < nkv; kvb++){
    const int kv0 = kvb*64;
    __syncthreads();
    #pragma unroll
    for (int i = 0; i < 2; i++){
      int row = wave*16 + i*8 + rloc;
      int src = cc ^ (row & 7);
      async_copy16(k  + ((size_t)bh*SEQ + kv0 + row)*HD + src*8,
                   Ks + (wave*16 + i*8)*128);
      async_copy16(vt + ((size_t)bh*HD + row)*SEQ + kv0 + src*8,
                   Vs + (wave*16 + i*8)*128);
    }
    __syncthreads();
    if (kv0 > q0 + 31) continue;   // fully masked for this wave (barriers stay matched)

    // ---- S = Q K^T ----
    f32x4 s[2][4] = {};
    short8 bk[4][2];
    #pragma unroll
    for (int ni = 0; ni < 4; ni++)
      #pragma unroll
      for (int ks = 0; ks < 2; ks++){
        int kv = ni*16 + lr;
        int byt = (ks*64 + lg*16) ^ ((kv&7)<<4);
        bk[ni][ks] = *(const short8*)(Ks + kv*128 + byt);
      }
    #pragma unroll
    for (int mi = 0; mi < 2; mi++)
      #pragma unroll
      for (int ni = 0; ni < 4; ni++){
        s[mi][ni] = __builtin_amdgcn_mfma_f32_16x16x32_bf16(aq[mi][0], bk[ni][0], s[mi][ni], 0,0,0);
        s[mi][ni] = __builtin_amdgcn_mfma_f32_16x16x32_bf16(aq[mi][1], bk[ni][1], s[mi][ni], 0,0,0);
      }

    // ---- scale + causal mask ----
    #pragma unroll
    for (int mi = 0; mi < 2; mi++)
      #pragma unroll
      for (int ni = 0; ni < 4; ni++)
        #pragma unroll
        for (int j = 0; j < 4; j++){
          int row = q0 + mi*16 + lg*4 + j;
          int col = kv0 + ni*16 + lr;
          float v = s[mi][ni][j] * 0.125f;
          s[mi][ni][j] = (col <= row) ? v : -1e30f;
        }

    // ---- online softmax ----
    float alpha[2][4], mnew[2][4];
    #pragma unroll
    for (int mi = 0; mi < 2; mi++)
      #pragma unroll
      for (int j = 0; j < 4; j++){
        float v = fmaxf(fmaxf(s[mi][0][j], s[mi][1][j]), fmaxf(s[mi][2][j], s[mi][3][j]));
        v = fmaxf(v, __shfl_xor(v, 1));
        v = fmaxf(v, __shfl_xor(v, 2));
        v = fmaxf(v, __shfl_xor(v, 4));
        v = fmaxf(v, __shfl_xor(v, 8));
        float mn = fmaxf(mrow[mi][j], v);
        alpha[mi][j] = __expf(mrow[mi][j] - mn);
        mnew[mi][j] = mn;
        mrow[mi][j] = mn;
      }

    // P = exp(s - mnew): accumulate row sums + write bf16 P to per-wave LDS (swizzled)
    float psum[2][4] = {};
    #pragma unroll
    for (int mi = 0; mi < 2; mi++)
      #pragma unroll
      for (int ni = 0; ni < 4; ni++)
        #pragma unroll
        for (int j = 0; j < 4; j++){
          float p = __expf(s[mi][ni][j] - mnew[mi][j]);
          psum[mi][j] += p;
          int row = mi*16 + lg*4 + j;
          int colb = (ni*16 + lr)*2;
          *(u16*)(Ps + wave*4096 + row*128 + (colb ^ ((row&7)<<4))) = f2bf(p);
        }
    #pragma unroll
    for (int mi = 0; mi < 2; mi++)
      #pragma unroll
      for (int j = 0; j < 4; j++){
        float v = psum[mi][j];
        v += __shfl_xor(v, 1);
        v += __shfl_xor(v, 2);
        v += __shfl_xor(v, 4);
        v += __shfl_xor(v, 8);
        lsum[mi][j] = lsum[mi][j]*alpha[mi][j] + v;
      }
    #pragma unroll
    for (int mi = 0; mi < 2; mi++)
      #pragma unroll
      for (int ni = 0; ni < 4; ni++)
        #pragma unroll
        for (int j = 0; j < 4; j++)
          o[mi][ni][j] *= alpha[mi][j];

    // ---- O += P V  (P from LDS as A-frags, V^T from LDS as B-frags) ----
    short8 pa[2][2], bv[4][2];
    #pragma unroll
    for (int mi = 0; mi < 2; mi++)
      #pragma unroll
      for (int ks = 0; ks < 2; ks++){
        int row = mi*16 + lr;
        int byt = (ks*64 + lg*16) ^ ((row&7)<<4);
        pa[mi][ks] = *(const short8*)(Ps + wave*4096 + row*128 + byt);
      }
    #pragma unroll
    for (int ni = 0; ni < 4; ni++)
      #pragma unroll
      for (int ks = 0; ks < 2; ks++){
        int d = ni*16 + lr;
        int byt = (ks*64 + lg*16) ^ ((d&7)<<4);
        bv[ni][ks] = *(const short8*)(Vs + d*128 + byt);
      }
    #pragma unroll
    for (int mi = 0; mi < 2; mi++)
      #pragma unroll
      for (int ni = 0; ni < 4; ni++){
        o[mi][ni] = __builtin_amdgcn_mfma_f32_16x16x32_bf16(pa[mi][0], bv[ni][0], o[mi][ni], 0,0,0);
        o[mi][ni] = __builtin_amdgcn_mfma_f32_16x16x32_bf16(pa[mi][1], bv[ni][1], o[mi][ni], 0,0,0);
      }
  }

  // epilogue: aout[b][s][h*64+d] bf16
  const int b_ = bh / NH, h = bh % NH;
  #pragma unroll
  for (int mi = 0; mi < 2; mi++)
    #pragma unroll
    for (int j = 0; j < 4; j++){
      float inv = 1.0f / lsum[mi][j];
      int qrow = q0 + mi*16 + lg*4 + j;
      #pragma unroll
      for (int ni = 0; ni < 4; ni++)
        aout[((size_t)b_*SEQ + qrow)*D_MODEL + h*HD + ni*16 + lr] = f2bf(o[mi][ni][j]*inv);
    }
}

extern "C" void kernel_launch(void* const* d_in, const int* in_sizes, int n_in,
                              void* d_out, int out_size, void* d_ws, size_t ws_size,
                              hipStream_t stream)
{
  const float* x    = (const float*)d_in[0];
  const float* Wqkv = (const float*)d_in[1];
  const float* bqkv = (const float*)d_in[2];
  const float* Wout = (const float*)d_in[3];
  const float* bout = (const float*)d_in[4];
  float* out = (float*)d_out;
  char* ws = (char*)d_ws;

  // workspace layout (bytes)
  u16* x_bf   = (u16*)(ws + 0);          // 8192x768   bf16 = 12,582,912
  u16* wqkv_t = (u16*)(ws + 12582912);   // 2304x768   bf16 =  3,538,944
  u16* wout_t = (u16*)(ws + 16121856);   //  768x768   bf16 =  1,179,648
  u16* qb     = (u16*)(ws + 17301504);   // [48][2048][64]  = 12,582,912
  u16* kb     = (u16*)(ws + 29884416);   // [48][2048][64]  = 12,582,912
  u16* vtb    = (u16*)(ws + 42467328);   // [48][64][2048]  = 12,582,912
  u16* attnb  = (u16*)(ws + 55050240);   // 8192x768   bf16 = 12,582,912

  cast4_kernel<<<6144, 256, 0, stream>>>(x, x_bf, (BATCH*SEQ*D_MODEL)/4);
  transpose_cast_kernel<<<dim3(12, 36), 256, 0, stream>>>(Wqkv, wqkv_t, 768, 2304);
  transpose_cast_kernel<<<dim3(12, 12), 256, 0, stream>>>(Wout, wout_t, 768, 768);

  gemm_bf16<1><<<dim3(64, 18), 256, 0, stream>>>(x_bf, wqkv_t, bqkv, nullptr,
                                                 qb, kb, vtb, MROWS, 3*D_MODEL, D_MODEL);

  attn_kernel<<<dim3(16, BHN), 256, 0, stream>>>(qb, kb, vtb, attnb);

  gemm_bf16<0><<<dim3(64, 6), 256, 0, stream>>>(attnb, wout_t, bout, out,
                                                nullptr, nullptr, nullptr, MROWS, D_MODEL, D_MODEL);
}

// Round 2
// 261.692 us; speedup vs baseline: 1.0720x; 1.0720x over previous
//
#include <hip/hip_runtime.h>
#include <hip/hip_bf16.h>

// Problem constants
#define D_MODEL 768
#define NH 12
#define HD 64
#define BATCH 4
#define SEQ 2048
#define BHN (BATCH*NH)        // 48
#define MROWS (BATCH*SEQ)     // 8192

typedef unsigned short u16;
typedef __attribute__((ext_vector_type(8))) short short8;
typedef __attribute__((ext_vector_type(4))) float f32x4;

__device__ inline u16 f2bf(float f){
  union { __hip_bfloat16 h; u16 u; } cv; cv.h = __float2bfloat16(f); return cv.u;
}

// async global->LDS, 16B per lane. LDS dest = wave-uniform base + lane*16.
__device__ inline void async_copy16(const void* g, void* l){
  __builtin_amdgcn_global_load_lds(
      (const __attribute__((address_space(1))) void*)g,
      (__attribute__((address_space(3))) void*)l, 16, 0, 0);
}

// ---------------- cast fp32 -> bf16, vectorized x4 ----------------
__global__ void cast4_kernel(const float* __restrict__ in, u16* __restrict__ out, int n4){
  int i = blockIdx.x*blockDim.x + threadIdx.x;
  if (i < n4){
    const float4 v = ((const float4*)in)[i];
    ushort4 o;
    o.x = f2bf(v.x); o.y = f2bf(v.y); o.z = f2bf(v.z); o.w = f2bf(v.w);
    ((ushort4*)out)[i] = o;
  }
}

// ---------------- transpose + cast: W[K][N] fp32 -> Wt[N][K] bf16 ----------------
__global__ void transpose_cast_kernel(const float* __restrict__ w, u16* __restrict__ wt,
                                      int K, int N){
  __shared__ u16 tile[64][65];
  int k0 = blockIdx.x*64, n0 = blockIdx.y*64;
  int c = threadIdx.x & 63, r0 = threadIdx.x >> 6;
  #pragma unroll
  for (int r = r0; r < 64; r += 4)
    tile[c][r] = f2bf(w[(size_t)(k0+r)*N + n0 + c]);
  __syncthreads();
  #pragma unroll
  for (int r = r0; r < 64; r += 4)
    wt[(size_t)(n0+r)*K + k0 + c] = tile[r][c];
}

// ---------------- bf16 GEMM: C[M,N] = A[M,K] @ Bt[N,K]^T ----------------
// 128x128 tile, BK=32, double-buffered LDS, 2-phase prefetch (raw s_barrier +
// asm vmcnt so the prefetch survives the barrier). 4 waves in 2x2, 4x4 frags.
template<int EPI>
__launch_bounds__(256)
__global__ void gemm_bf16(const u16* __restrict__ A, const u16* __restrict__ Bt,
                          const float* __restrict__ bias, float* __restrict__ outf,
                          u16* __restrict__ oq, u16* __restrict__ ok, u16* __restrict__ ovt,
                          int M, int N, int K)
{
  __shared__ alignas(16) char smem[32768];   // As0,As1,Bs0,Bs1: 8KB each
  const int tid = threadIdx.x, wave = tid>>6, lane = tid&63;
  const int lr = lane&15, lg = lane>>4;
  const int m0 = blockIdx.x*128, n0 = blockIdx.y*128;
  const int wr = (wave>>1)*64, wc = (wave&1)*64;
  f32x4 acc[4][4] = {};
  const int srow = wave*32 + (lane>>2);   // staging row (+i*16)
  const int schk = lane&3;                // 16B chunk within 64B row

  auto stage = [&](int kt, int buf){
    char* Ab = smem + buf*8192;
    char* Bb = smem + 16384 + buf*8192;
    #pragma unroll
    for (int i = 0; i < 2; i++){
      int r = srow + i*16;
      async_copy16(A  + (size_t)(m0 + r)*K + kt + schk*8, Ab + (wave*32 + i*16)*64);
      async_copy16(Bt + (size_t)(n0 + r)*K + kt + schk*8, Bb + (wave*32 + i*16)*64);
    }
  };

  const int NT = K >> 5;
  stage(0, 0);
  for (int t = 0; t < NT; t++){
    const int c = t & 1;
    asm volatile("s_waitcnt vmcnt(0)" ::: "memory");
    __builtin_amdgcn_s_barrier();
    if (t+1 < NT) stage((t+1)<<5, c^1);

    const char* Ac = smem + c*8192;
    const char* Bc = smem + 16384 + c*8192;
    short8 a[4], b[4];
    #pragma unroll
    for (int mi = 0; mi < 4; mi++)
      a[mi] = *(const short8*)(Ac + (wr + mi*16 + lr)*64 + lg*16);
    #pragma unroll
    for (int ni = 0; ni < 4; ni++)
      b[ni] = *(const short8*)(Bc + (wc + ni*16 + lr)*64 + lg*16);
    #pragma unroll
    for (int mi = 0; mi < 4; mi++)
      #pragma unroll
      for (int ni = 0; ni < 4; ni++)
        acc[mi][ni] = __builtin_amdgcn_mfma_f32_16x16x32_bf16(a[mi], b[ni], acc[mi][ni], 0, 0, 0);
  }

  // epilogue: C row = (lane>>4)*4 + j, col = lane&15  [verified C/D layout]
  #pragma unroll
  for (int mi = 0; mi < 4; mi++)
  #pragma unroll
  for (int ni = 0; ni < 4; ni++)
  #pragma unroll
  for (int j = 0; j < 4; j++){
    int m = m0 + wr + mi*16 + lg*4 + j;
    int n = n0 + wc + ni*16 + lr;
    float v = acc[mi][ni][j] + bias[n];
    if (EPI == 0){
      outf[(size_t)m*N + n] = v;
    } else {
      int b_ = m >> 11, s = m & 2047;
      int t  = (n >= 1536) ? 2 : (n >= 768 ? 1 : 0);
      int hn = n - t*768;
      int h = hn >> 6, d = hn & 63;
      u16 bf = f2bf(v);
      size_t base = (size_t)(b_*NH + h);
      if (t == 0)      oq [(base*SEQ + s)*HD + d] = bf;
      else if (t == 1) ok [(base*SEQ + s)*HD + d] = bf;
      else             ovt[(base*HD + d)*SEQ + s] = bf;   // V stored transposed
    }
  }
}

// ---------------- flash attention, causal-paired, double-buffered ----------------
// 768 blocks x 128 threads (2 waves x 32 q rows). Block handles Q-tile pair
// (qt=31-j then qt=j) of 64 rows each -> uniform 33 KV64-steps per block.
// K/V LDS double-buffered; per step: [vmcnt(0); s_barrier; stage(next); compute].
// XCD swizzle: bh % 8 == block_id % 8 so each XCD's L2 keeps its 6 heads' K/V.
__launch_bounds__(128)
__global__ void attn_kernel(const u16* __restrict__ q, const u16* __restrict__ k,
                            const u16* __restrict__ vt, u16* __restrict__ aout)
{
  __shared__ alignas(16) char smem[40960];
  // K0 @0, K1 @8192, V0 @16384, V1 @24576, P @32768 (+wave*4096)

  const int b1 = blockIdx.x;                 // 0..767
  const int xcd = b1 & 7, slot = b1 >> 3;    // slot 0..95
  const int bh = xcd + 8*(slot >> 4);        // 6 heads per XCD
  const int jp = slot & 15;                  // pair index 0..15
  const int tid = threadIdx.x, wave = tid>>6, lane = tid&63;
  const int lr = lane&15, lg = lane>>4;
  const int rloc = lane>>3, cc = lane&7;
  const int b_ = bh / NH, h = bh % NH;
  char* Ps = smem + 32768 + wave*4096;

  auto stageKV = [&](int kv0, int buf){
    char* Kb = smem + buf*8192;
    char* Vb = smem + 16384 + buf*8192;
    #pragma unroll
    for (int i = 0; i < 4; i++){
      int row = wave*32 + i*8 + rloc;
      int src = cc ^ (row & 7);
      async_copy16(k  + ((size_t)bh*SEQ + kv0 + row)*HD + src*8, Kb + (wave*32 + i*8)*128);
      async_copy16(vt + ((size_t)bh*HD + row)*SEQ + kv0 + src*8, Vb + (wave*32 + i*8)*128);
    }
  };

  #pragma unroll 1
  for (int half = 0; half < 2; half++){
    const int qt = half ? jp : (31 - jp);    // 64-row Q tile index
    const int nkv = qt + 1;                  // KV64 steps
    const int q0 = qt*64 + wave*32;

    // Q fragments straight from global (one-time per tile)
    short8 aq[2][2];
    #pragma unroll
    for (int mi = 0; mi < 2; mi++)
      #pragma unroll
      for (int ks = 0; ks < 2; ks++){
        int row = q0 + mi*16 + lr;
        aq[mi][ks] = *(const short8*)(q + ((size_t)bh*SEQ + row)*HD + ks*32 + lg*8);
      }

    float mrow[2][4], lsum[2][4];
    f32x4 o[2][4] = {};
    #pragma unroll
    for (int mi = 0; mi < 2; mi++)
      #pragma unroll
      for (int jj = 0; jj < 4; jj++){ mrow[mi][jj] = -INFINITY; lsum[mi][jj] = 0.f; }

    __builtin_amdgcn_s_barrier();   // protect buf0 from previous half's readers
    stageKV(0, 0);

    for (int kvb = 0; kvb < nkv; kvb++){
      const int c = kvb & 1;
      const int kv0 = kvb*64;
      asm volatile("s_waitcnt vmcnt(0)" ::: "memory");
      __builtin_amdgcn_s_barrier();
      if (kvb+1 < nkv) stageKV(kv0 + 64, c^1);

      const char* Ks = smem + c*8192;
      const char* Vs = smem + 16384 + c*8192;

      // ---- S = Q K^T ----
      f32x4 s[2][4] = {};
      short8 bk[4][2];
      #pragma unroll
      for (int ni = 0; ni < 4; ni++)
        #pragma unroll
        for (int ks = 0; ks < 2; ks++){
          int kv = ni*16 + lr;
          int byt = (ks*64 + lg*16) ^ ((kv&7)<<4);
          bk[ni][ks] = *(const short8*)(Ks + kv*128 + byt);
        }
      #pragma unroll
      for (int mi = 0; mi < 2; mi++)
        #pragma unroll
        for (int ni = 0; ni < 4; ni++){
          s[mi][ni] = __builtin_amdgcn_mfma_f32_16x16x32_bf16(aq[mi][0], bk[ni][0], s[mi][ni], 0,0,0);
          s[mi][ni] = __builtin_amdgcn_mfma_f32_16x16x32_bf16(aq[mi][1], bk[ni][1], s[mi][ni], 0,0,0);
        }

      // ---- scale (+ causal mask on diagonal steps only) ----
      if (kv0 + 63 > q0){
        #pragma unroll
        for (int mi = 0; mi < 2; mi++)
          #pragma unroll
          for (int ni = 0; ni < 4; ni++)
            #pragma unroll
            for (int jj = 0; jj < 4; jj++){
              int row = q0 + mi*16 + lg*4 + jj;
              int col = kv0 + ni*16 + lr;
              float v = s[mi][ni][jj] * 0.125f;
              s[mi][ni][jj] = (col <= row) ? v : -1e30f;
            }
      } else {
        #pragma unroll
        for (int mi = 0; mi < 2; mi++)
          #pragma unroll
          for (int ni = 0; ni < 4; ni++)
            #pragma unroll
            for (int jj = 0; jj < 4; jj++)
              s[mi][ni][jj] *= 0.125f;
      }

      // ---- online softmax ----
      float alpha[2][4], mnew[2][4];
      #pragma unroll
      for (int mi = 0; mi < 2; mi++)
        #pragma unroll
        for (int jj = 0; jj < 4; jj++){
          float v = fmaxf(fmaxf(s[mi][0][jj], s[mi][1][jj]), fmaxf(s[mi][2][jj], s[mi][3][jj]));
          v = fmaxf(v, __shfl_xor(v, 1));
          v = fmaxf(v, __shfl_xor(v, 2));
          v = fmaxf(v, __shfl_xor(v, 4));
          v = fmaxf(v, __shfl_xor(v, 8));
          float mn = fmaxf(mrow[mi][jj], v);
          alpha[mi][jj] = __expf(mrow[mi][jj] - mn);
          mnew[mi][jj] = mn;
          mrow[mi][jj] = mn;
        }

      // P = exp(s - mnew): row sums + bf16 P to per-wave LDS (swizzled)
      float psum[2][4] = {};
      #pragma unroll
      for (int mi = 0; mi < 2; mi++)
        #pragma unroll
        for (int ni = 0; ni < 4; ni++)
          #pragma unroll
          for (int jj = 0; jj < 4; jj++){
            float p = __expf(s[mi][ni][jj] - mnew[mi][jj]);
            psum[mi][jj] += p;
            int row = mi*16 + lg*4 + jj;
            int colb = (ni*16 + lr)*2;
            *(u16*)(Ps + row*128 + (colb ^ ((row&7)<<4))) = f2bf(p);
          }
      #pragma unroll
      for (int mi = 0; mi < 2; mi++)
        #pragma unroll
        for (int jj = 0; jj < 4; jj++){
          float v = psum[mi][jj];
          v += __shfl_xor(v, 1);
          v += __shfl_xor(v, 2);
          v += __shfl_xor(v, 4);
          v += __shfl_xor(v, 8);
          lsum[mi][jj] = lsum[mi][jj]*alpha[mi][jj] + v;
        }
      #pragma unroll
      for (int mi = 0; mi < 2; mi++)
        #pragma unroll
        for (int ni = 0; ni < 4; ni++)
          #pragma unroll
          for (int jj = 0; jj < 4; jj++)
            o[mi][ni][jj] *= alpha[mi][jj];

      // ---- O += P V ----
      short8 pa[2][2], bv[4][2];
      #pragma unroll
      for (int mi = 0; mi < 2; mi++)
        #pragma unroll
        for (int ks = 0; ks < 2; ks++){
          int row = mi*16 + lr;
          int byt = (ks*64 + lg*16) ^ ((row&7)<<4);
          pa[mi][ks] = *(const short8*)(Ps + row*128 + byt);
        }
      #pragma unroll
      for (int ni = 0; ni < 4; ni++)
        #pragma unroll
        for (int ks = 0; ks < 2; ks++){
          int d = ni*16 + lr;
          int byt = (ks*64 + lg*16) ^ ((d&7)<<4);
          bv[ni][ks] = *(const short8*)(Vs + d*128 + byt);
        }
      #pragma unroll
      for (int mi = 0; mi < 2; mi++)
        #pragma unroll
        for (int ni = 0; ni < 4; ni++){
          o[mi][ni] = __builtin_amdgcn_mfma_f32_16x16x32_bf16(pa[mi][0], bv[ni][0], o[mi][ni], 0,0,0);
          o[mi][ni] = __builtin_amdgcn_mfma_f32_16x16x32_bf16(pa[mi][1], bv[ni][1], o[mi][ni], 0,0,0);
        }
    }

    // epilogue for this half: aout[b][s][h*64+d] bf16
    #pragma unroll
    for (int mi = 0; mi < 2; mi++)
      #pragma unroll
      for (int jj = 0; jj < 4; jj++){
        float inv = 1.0f / lsum[mi][jj];
        int qrow = q0 + mi*16 + lg*4 + jj;
        #pragma unroll
        for (int ni = 0; ni < 4; ni++)
          aout[((size_t)b_*SEQ + qrow)*D_MODEL + h*HD + ni*16 + lr] = f2bf(o[mi][ni][jj]*inv);
      }
  }
}

extern "C" void kernel_launch(void* const* d_in, const int* in_sizes, int n_in,
                              void* d_out, int out_size, void* d_ws, size_t ws_size,
                              hipStream_t stream)
{
  const float* x    = (const float*)d_in[0];
  const float* Wqkv = (const float*)d_in[1];
  const float* bqkv = (const float*)d_in[2];
  const float* Wout = (const float*)d_in[3];
  const float* bout = (const float*)d_in[4];
  float* out = (float*)d_out;
  char* ws = (char*)d_ws;

  // workspace layout (bytes)
  u16* x_bf   = (u16*)(ws + 0);          // 8192x768   bf16 = 12,582,912
  u16* wqkv_t = (u16*)(ws + 12582912);   // 2304x768   bf16 =  3,538,944
  u16* wout_t = (u16*)(ws + 16121856);   //  768x768   bf16 =  1,179,648
  u16* qb     = (u16*)(ws + 17301504);   // [48][2048][64]  = 12,582,912
  u16* kb     = (u16*)(ws + 29884416);   // [48][2048][64]  = 12,582,912
  u16* vtb    = (u16*)(ws + 42467328);   // [48][64][2048]  = 12,582,912
  u16* attnb  = (u16*)(ws + 55050240);   // 8192x768   bf16 = 12,582,912

  cast4_kernel<<<6144, 256, 0, stream>>>(x, x_bf, (BATCH*SEQ*D_MODEL)/4);
  transpose_cast_kernel<<<dim3(12, 36), 256, 0, stream>>>(Wqkv, wqkv_t, 768, 2304);
  transpose_cast_kernel<<<dim3(12, 12), 256, 0, stream>>>(Wout, wout_t, 768, 768);

  gemm_bf16<1><<<dim3(64, 18), 256, 0, stream>>>(x_bf, wqkv_t, bqkv, nullptr,
                                                 qb, kb, vtb, MROWS, 3*D_MODEL, D_MODEL);

  attn_kernel<<<768, 128, 0, stream>>>(qb, kb, vtb, attnb);

  gemm_bf16<0><<<dim3(64, 6), 256, 0, stream>>>(attnb, wout_t, bout, out,
                                                nullptr, nullptr, nullptr, MROWS, D_MODEL, D_MODEL);
}

// Round 3
// 221.004 us; speedup vs baseline: 1.2694x; 1.1841x over previous
//
#include <hip/hip_runtime.h>
#include <hip/hip_bf16.h>

// Problem constants
#define D_MODEL 768
#define NH 12
#define HD 64
#define BATCH 4
#define SEQ 2048
#define BHN (BATCH*NH)        // 48
#define MROWS (BATCH*SEQ)     // 8192

typedef unsigned short u16;
typedef __attribute__((ext_vector_type(8))) short short8;
typedef __attribute__((ext_vector_type(4))) float f32x4;

__device__ inline u16 f2bf(float f){
  union { __hip_bfloat16 h; u16 u; } cv; cv.h = __float2bfloat16(f); return cv.u;
}

// async global->LDS, 16B per lane. LDS dest = wave-uniform base + lane*16.
__device__ inline void async_copy16(const void* g, void* l){
  __builtin_amdgcn_global_load_lds(
      (const __attribute__((address_space(1))) void*)g,
      (__attribute__((address_space(3))) void*)l, 16, 0, 0);
}

// ---------------- cast fp32 -> bf16, vectorized x4 ----------------
__global__ void cast4_kernel(const float* __restrict__ in, u16* __restrict__ out, int n4){
  int i = blockIdx.x*blockDim.x + threadIdx.x;
  if (i < n4){
    const float4 v = ((const float4*)in)[i];
    ushort4 o;
    o.x = f2bf(v.x); o.y = f2bf(v.y); o.z = f2bf(v.z); o.w = f2bf(v.w);
    ((ushort4*)out)[i] = o;
  }
}

// ---------------- transpose + cast: W[K][N] fp32 -> Wt[N][K] bf16 ----------------
__global__ void transpose_cast_kernel(const float* __restrict__ w, u16* __restrict__ wt,
                                      int K, int N){
  __shared__ u16 tile[64][65];
  int k0 = blockIdx.x*64, n0 = blockIdx.y*64;
  int c = threadIdx.x & 63, r0 = threadIdx.x >> 6;
  #pragma unroll
  for (int r = r0; r < 64; r += 4)
    tile[c][r] = f2bf(w[(size_t)(k0+r)*N + n0 + c]);
  __syncthreads();
  #pragma unroll
  for (int r = r0; r < 64; r += 4)
    wt[(size_t)(n0+r)*K + k0 + c] = tile[r][c];
}

// ---------------- bf16 GEMM: C[M,N] = A[M,K] @ Bt[N,K]^T ----------------
// 128x128 tile, BK=32, double-buffered LDS, 2-phase prefetch.
template<int EPI>
__launch_bounds__(256)
__global__ void gemm_bf16(const u16* __restrict__ A, const u16* __restrict__ Bt,
                          const float* __restrict__ bias, float* __restrict__ outf,
                          u16* __restrict__ oq, u16* __restrict__ ok, u16* __restrict__ ovt,
                          int M, int N, int K)
{
  __shared__ alignas(16) char smem[32768];   // As0,As1,Bs0,Bs1: 8KB each
  const int tid = threadIdx.x, wave = tid>>6, lane = tid&63;
  const int lr = lane&15, lg = lane>>4;
  const int m0 = blockIdx.x*128, n0 = blockIdx.y*128;
  const int wr = (wave>>1)*64, wc = (wave&1)*64;
  f32x4 acc[4][4] = {};
  const int srow = wave*32 + (lane>>2);   // staging row (+i*16)
  const int schk = lane&3;                // 16B chunk within 64B row

  auto stage = [&](int kt, int buf){
    char* Ab = smem + buf*8192;
    char* Bb = smem + 16384 + buf*8192;
    #pragma unroll
    for (int i = 0; i < 2; i++){
      int r = srow + i*16;
      async_copy16(A  + (size_t)(m0 + r)*K + kt + schk*8, Ab + (wave*32 + i*16)*64);
      async_copy16(Bt + (size_t)(n0 + r)*K + kt + schk*8, Bb + (wave*32 + i*16)*64);
    }
  };

  const int NT = K >> 5;
  stage(0, 0);
  for (int t = 0; t < NT; t++){
    const int c = t & 1;
    asm volatile("s_waitcnt vmcnt(0)" ::: "memory");
    __builtin_amdgcn_s_barrier();
    if (t+1 < NT) stage((t+1)<<5, c^1);

    const char* Ac = smem + c*8192;
    const char* Bc = smem + 16384 + c*8192;
    short8 a[4], b[4];
    #pragma unroll
    for (int mi = 0; mi < 4; mi++)
      a[mi] = *(const short8*)(Ac + (wr + mi*16 + lr)*64 + lg*16);
    #pragma unroll
    for (int ni = 0; ni < 4; ni++)
      b[ni] = *(const short8*)(Bc + (wc + ni*16 + lr)*64 + lg*16);
    #pragma unroll
    for (int mi = 0; mi < 4; mi++)
      #pragma unroll
      for (int ni = 0; ni < 4; ni++)
        acc[mi][ni] = __builtin_amdgcn_mfma_f32_16x16x32_bf16(a[mi], b[ni], acc[mi][ni], 0, 0, 0);
  }

  // epilogue: C row = (lane>>4)*4 + j, col = lane&15  [verified C/D layout]
  #pragma unroll
  for (int mi = 0; mi < 4; mi++)
  #pragma unroll
  for (int ni = 0; ni < 4; ni++)
  #pragma unroll
  for (int j = 0; j < 4; j++){
    int m = m0 + wr + mi*16 + lg*4 + j;
    int n = n0 + wc + ni*16 + lr;
    float v = acc[mi][ni][j] + bias[n];
    if (EPI == 0){
      outf[(size_t)m*N + n] = v;
    } else {
      int b_ = m >> 11, s = m & 2047;
      int t  = (n >= 1536) ? 2 : (n >= 768 ? 1 : 0);
      int hn = n - t*768;
      int h = hn >> 6, d = hn & 63;
      u16 bf = f2bf(v);
      size_t base = (size_t)(b_*NH + h);
      if (t == 0)      oq [(base*SEQ + s)*HD + d] = bf;
      else if (t == 1) ok [(base*SEQ + s)*HD + d] = bf;
      else             ovt[(base*HD + d)*SEQ + s] = bf;   // V stored transposed
    }
  }
}

// ---------------- flash attention: barrier-free, per-wave independent ----------------
// 384 blocks x 256 threads = 1536 waves. Each wave owns 32 q-rows (tile pair
// p, 63-p -> uniform 33 KV64 steps). K/V loaded global->VGPR directly (L2-resident
// per XCD: bh = xcd*6 + ...). NO __syncthreads anywhere: waves run free, load
// latency hides under softmax/PV of the same wave + TLP from 6 waves/CU.
// P bounces through per-wave LDS (4KB each) - wave-local, no sync needed.
__launch_bounds__(256, 2)
__global__ void attn_kernel(const u16* __restrict__ q, const u16* __restrict__ k,
                            const u16* __restrict__ vt, u16* __restrict__ aout)
{
  __shared__ alignas(16) char Ps_all[16384];   // 4 waves x 4KB
  const int b1 = blockIdx.x;                 // 0..383
  const int xcd = b1 & 7, grp = b1 >> 3;     // grp 0..47
  const int bh = xcd*6 + (grp >> 3);         // 6 heads per XCD
  const int pairblk = grp & 7;               // 0..7
  const int tid = threadIdx.x, wave = tid>>6, lane = tid&63;
  const int pr = pairblk*4 + wave;           // pair index 0..31
  const int lr = lane&15, lg = lane>>4;
  char* Ps = Ps_all + wave*4096;
  const int b_ = bh / NH, h = bh % NH;
  const u16* qp = q  + (size_t)bh*SEQ*HD;
  const u16* kp = k  + (size_t)bh*SEQ*HD;
  const u16* vp = vt + (size_t)bh*HD*SEQ;
  const float SC = 0.125f * 1.44269504f;     // scale * log2(e), use exp2

  #pragma unroll 1
  for (int half = 0; half < 2; half++){
    const int t = half ? (63 - pr) : pr;     // 32-row tile index 0..63
    const int q0 = t*32;
    const int nkv = (t >> 1) + 1;            // KV64 steps

    // Q fragments (A-frag: m=lr, k = ks*32+lg*8)
    short8 aq[2][2];
    #pragma unroll
    for (int mi = 0; mi < 2; mi++)
      #pragma unroll
      for (int ks = 0; ks < 2; ks++)
        aq[mi][ks] = *(const short8*)(qp + (size_t)(q0 + mi*16 + lr)*HD + ks*32 + lg*8);

    float mrow[2][4], lsum[2][4];
    f32x4 o[2][4] = {};
    #pragma unroll
    for (int mi = 0; mi < 2; mi++)
      #pragma unroll
      for (int jj = 0; jj < 4; jj++){ mrow[mi][jj] = -INFINITY; lsum[mi][jj] = 0.f; }

    // prologue: K tile 0 -> regs (B-frag: n=kv row, k=d)
    short8 bk[4][2];
    #pragma unroll
    for (int ni = 0; ni < 4; ni++)
      #pragma unroll
      for (int ks = 0; ks < 2; ks++)
        bk[ni][ks] = *(const short8*)(kp + (size_t)(ni*16 + lr)*HD + ks*32 + lg*8);

    #pragma unroll 1
    for (int kvb = 0; kvb < nkv; kvb++){
      const int kv0 = kvb*64;

      // issue V tile loads early (B-frag from V^T: n=d, k=kv)
      short8 bv[4][2];
      #pragma unroll
      for (int ni = 0; ni < 4; ni++)
        #pragma unroll
        for (int ks = 0; ks < 2; ks++)
          bv[ni][ks] = *(const short8*)(vp + (size_t)(ni*16 + lr)*SEQ + kv0 + ks*32 + lg*8);

      // ---- S = Q K^T ----
      f32x4 s[2][4] = {};
      #pragma unroll
      for (int mi = 0; mi < 2; mi++)
        #pragma unroll
        for (int ni = 0; ni < 4; ni++){
          s[mi][ni] = __builtin_amdgcn_mfma_f32_16x16x32_bf16(aq[mi][0], bk[ni][0], s[mi][ni], 0,0,0);
          s[mi][ni] = __builtin_amdgcn_mfma_f32_16x16x32_bf16(aq[mi][1], bk[ni][1], s[mi][ni], 0,0,0);
        }

      // prefetch next K tile into bk (latency hides under softmax+PV)
      if (kvb+1 < nkv){
        #pragma unroll
        for (int ni = 0; ni < 4; ni++)
          #pragma unroll
          for (int ks = 0; ks < 2; ks++)
            bk[ni][ks] = *(const short8*)(kp + (size_t)(kv0 + 64 + ni*16 + lr)*HD + ks*32 + lg*8);
      }

      // ---- scale (+ causal mask on the final, diagonal step only) ----
      if (kvb == nkv-1){
        #pragma unroll
        for (int mi = 0; mi < 2; mi++)
          #pragma unroll
          for (int ni = 0; ni < 4; ni++)
            #pragma unroll
            for (int jj = 0; jj < 4; jj++){
              int row = q0 + mi*16 + lg*4 + jj;
              int col = kv0 + ni*16 + lr;
              float v = s[mi][ni][jj] * SC;
              s[mi][ni][jj] = (col <= row) ? v : -1e30f;
            }
      } else {
        #pragma unroll
        for (int mi = 0; mi < 2; mi++)
          #pragma unroll
          for (int ni = 0; ni < 4; ni++)
            #pragma unroll
            for (int jj = 0; jj < 4; jj++)
              s[mi][ni][jj] *= SC;
      }

      // ---- online softmax (log2 domain) ----
      float alpha[2][4], mnew[2][4];
      #pragma unroll
      for (int mi = 0; mi < 2; mi++)
        #pragma unroll
        for (int jj = 0; jj < 4; jj++){
          float v = fmaxf(fmaxf(s[mi][0][jj], s[mi][1][jj]), fmaxf(s[mi][2][jj], s[mi][3][jj]));
          v = fmaxf(v, __shfl_xor(v, 1));
          v = fmaxf(v, __shfl_xor(v, 2));
          v = fmaxf(v, __shfl_xor(v, 4));
          v = fmaxf(v, __shfl_xor(v, 8));
          float mn = fmaxf(mrow[mi][jj], v);
          alpha[mi][jj] = __builtin_amdgcn_exp2f(mrow[mi][jj] - mn);
          mnew[mi][jj] = mn;
          mrow[mi][jj] = mn;
        }

      // P = exp2(s - mnew): row sums + bf16 P to per-wave LDS (swizzled)
      float psum[2][4] = {};
      #pragma unroll
      for (int mi = 0; mi < 2; mi++)
        #pragma unroll
        for (int ni = 0; ni < 4; ni++)
          #pragma unroll
          for (int jj = 0; jj < 4; jj++){
            float p = __builtin_amdgcn_exp2f(s[mi][ni][jj] - mnew[mi][jj]);
            psum[mi][jj] += p;
            int row = mi*16 + lg*4 + jj;
            int colb = (ni*16 + lr)*2;
            *(u16*)(Ps + row*128 + (colb ^ ((row&7)<<4))) = f2bf(p);
          }
      #pragma unroll
      for (int mi = 0; mi < 2; mi++)
        #pragma unroll
        for (int jj = 0; jj < 4; jj++){
          float v = psum[mi][jj];
          v += __shfl_xor(v, 1);
          v += __shfl_xor(v, 2);
          v += __shfl_xor(v, 4);
          v += __shfl_xor(v, 8);
          lsum[mi][jj] = lsum[mi][jj]*alpha[mi][jj] + v;
        }
      #pragma unroll
      for (int mi = 0; mi < 2; mi++)
        #pragma unroll
        for (int ni = 0; ni < 4; ni++)
          #pragma unroll
          for (int jj = 0; jj < 4; jj++)
            o[mi][ni][jj] *= alpha[mi][jj];

      // ---- O += P V (P A-frags from wave-local LDS; no barrier, lgkmcnt only) ----
      short8 pa[2][2];
      #pragma unroll
      for (int mi = 0; mi < 2; mi++)
        #pragma unroll
        for (int ks = 0; ks < 2; ks++){
          int row = mi*16 + lr;
          int byt = (ks*64 + lg*16) ^ ((row&7)<<4);
          pa[mi][ks] = *(const short8*)(Ps + row*128 + byt);
        }
      #pragma unroll
      for (int mi = 0; mi < 2; mi++)
        #pragma unroll
        for (int ni = 0; ni < 4; ni++){
          o[mi][ni] = __builtin_amdgcn_mfma_f32_16x16x32_bf16(pa[mi][0], bv[ni][0], o[mi][ni], 0,0,0);
          o[mi][ni] = __builtin_amdgcn_mfma_f32_16x16x32_bf16(pa[mi][1], bv[ni][1], o[mi][ni], 0,0,0);
        }
    }

    // epilogue: aout[b][s][h*64+d] bf16
    #pragma unroll
    for (int mi = 0; mi < 2; mi++)
      #pragma unroll
      for (int jj = 0; jj < 4; jj++){
        float inv = 1.0f / lsum[mi][jj];
        int qrow = q0 + mi*16 + lg*4 + jj;
        #pragma unroll
        for (int ni = 0; ni < 4; ni++)
          aout[((size_t)b_*SEQ + qrow)*D_MODEL + h*HD + ni*16 + lr] = f2bf(o[mi][ni][jj]*inv);
      }
  }
}

extern "C" void kernel_launch(void* const* d_in, const int* in_sizes, int n_in,
                              void* d_out, int out_size, void* d_ws, size_t ws_size,
                              hipStream_t stream)
{
  const float* x    = (const float*)d_in[0];
  const float* Wqkv = (const float*)d_in[1];
  const float* bqkv = (const float*)d_in[2];
  const float* Wout = (const float*)d_in[3];
  const float* bout = (const float*)d_in[4];
  float* out = (float*)d_out;
  char* ws = (char*)d_ws;

  // workspace layout (bytes)
  u16* x_bf   = (u16*)(ws + 0);          // 8192x768   bf16 = 12,582,912
  u16* wqkv_t = (u16*)(ws + 12582912);   // 2304x768   bf16 =  3,538,944
  u16* wout_t = (u16*)(ws + 16121856);   //  768x768   bf16 =  1,179,648
  u16* qb     = (u16*)(ws + 17301504);   // [48][2048][64]  = 12,582,912
  u16* kb     = (u16*)(ws + 29884416);   // [48][2048][64]  = 12,582,912
  u16* vtb    = (u16*)(ws + 42467328);   // [48][64][2048]  = 12,582,912
  u16* attnb  = (u16*)(ws + 55050240);   // 8192x768   bf16 = 12,582,912

  cast4_kernel<<<6144, 256, 0, stream>>>(x, x_bf, (BATCH*SEQ*D_MODEL)/4);
  transpose_cast_kernel<<<dim3(12, 36), 256, 0, stream>>>(Wqkv, wqkv_t, 768, 2304);
  transpose_cast_kernel<<<dim3(12, 12), 256, 0, stream>>>(Wout, wout_t, 768, 768);

  gemm_bf16<1><<<dim3(64, 18), 256, 0, stream>>>(x_bf, wqkv_t, bqkv, nullptr,
                                                 qb, kb, vtb, MROWS, 3*D_MODEL, D_MODEL);

  attn_kernel<<<384, 256, 0, stream>>>(qb, kb, vtb, attnb);

  gemm_bf16<0><<<dim3(64, 6), 256, 0, stream>>>(attnb, wout_t, bout, out,
                                                nullptr, nullptr, nullptr, MROWS, D_MODEL, D_MODEL);
}